// Round 1
// baseline (112.783 us; speedup 1.0000x reference)
//
#include <hip/hip_runtime.h>

#define D 128
#define EPS 1e-5f

// Stage 1: btw[d] = sum_e embed[edge_idx[e][1], d] * weight[e]
__global__ __launch_bounds__(256) void btw_kernel(
    const float* __restrict__ embed,
    const float* __restrict__ weight,
    const int* __restrict__ eidx,
    float* __restrict__ btw,   // [128] in ws, pre-zeroed
    int nEdges)
{
    __shared__ float sbtw[D];
    const int tid = threadIdx.x;
    for (int i = tid; i < D; i += blockDim.x) sbtw[i] = 0.f;
    __syncthreads();

    const int j = tid & 31;                                   // lane within half-wave
    const int hwGlobal = blockIdx.x * (blockDim.x >> 5) + (tid >> 5);
    const int hwTotal  = gridDim.x * (blockDim.x >> 5);

    float4 acc = {0.f, 0.f, 0.f, 0.f};
    for (int e = hwGlobal; e < nEdges; e += hwTotal) {
        const int b   = eidx[2 * e + 1];
        const float w = weight[e];
        const float4 v = reinterpret_cast<const float4*>(embed + (size_t)b * D)[j];
        acc.x += w * v.x;
        acc.y += w * v.y;
        acc.z += w * v.z;
        acc.w += w * v.w;
    }
    // block-level reduce into LDS (all half-waves map lane j -> dims 4j..4j+3)
    atomicAdd(&sbtw[4 * j + 0], acc.x);
    atomicAdd(&sbtw[4 * j + 1], acc.y);
    atomicAdd(&sbtw[4 * j + 2], acc.z);
    atomicAdd(&sbtw[4 * j + 3], acc.w);
    __syncthreads();
    if (tid < D) unsafeAtomicAdd(&btw[tid], sbtw[tid]);
}

// Stage 2: out[e] = sigmoid(log(dot(embed[edge_idx[e][0], :], btw)) + EPS)
__global__ __launch_bounds__(256) void score_kernel(
    const float* __restrict__ embed,
    const int* __restrict__ eidx,
    const float* __restrict__ btw,
    float* __restrict__ out,
    int nEdges)
{
    const int tid = threadIdx.x;
    const int j = tid & 31;
    const int hwGlobal = blockIdx.x * (blockDim.x >> 5) + (tid >> 5);
    const int hwTotal  = gridDim.x * (blockDim.x >> 5);

    const float4 bt = reinterpret_cast<const float4*>(btw)[j];

    for (int e = hwGlobal; e < nEdges; e += hwTotal) {
        const int a = eidx[2 * e + 0];
        const float4 v = reinterpret_cast<const float4*>(embed + (size_t)a * D)[j];
        float s = v.x * bt.x + v.y * bt.y + v.z * bt.z + v.w * bt.w;
        // reduce across the 32-lane half-wave (xor masks < 32 stay in-half)
        #pragma unroll
        for (int m = 1; m < 32; m <<= 1)
            s += __shfl_xor(s, m, 64);
        if (j == 0) {
            const float x = logf(s) + EPS;
            out[e] = 1.f / (1.f + expf(-x));
        }
    }
}

extern "C" void kernel_launch(void* const* d_in, const int* in_sizes, int n_in,
                              void* d_out, int out_size, void* d_ws, size_t ws_size,
                              hipStream_t stream) {
    const float* embed  = (const float*)d_in[0];
    const float* weight = (const float*)d_in[1];
    const int*   eidx   = (const int*)d_in[2];
    float* out = (float*)d_out;
    float* btw = (float*)d_ws;

    const int nEdges = in_sizes[1];   // weight is (E,1) -> E elements

    hipMemsetAsync(d_ws, 0, D * sizeof(float), stream);
    btw_kernel<<<1024, 256, 0, stream>>>(embed, weight, eidx, btw, nEdges);
    score_kernel<<<2048, 256, 0, stream>>>(embed, eidx, btw, out, nEdges);
}

// Round 2
// 74.155 us; speedup vs baseline: 1.5209x; 1.5209x over previous
//
#include <hip/hip_runtime.h>

#define D 128
#define EPS 1e-5f

// k1: wsum[n] = sum of weight over edges whose dst == n
__global__ __launch_bounds__(256) void wsum_kernel(
    const float* __restrict__ weight,
    const int* __restrict__ eidx,
    float* __restrict__ wsum,   // [nNodes], pre-zeroed
    int nEdges)
{
    const int e = blockIdx.x * blockDim.x + threadIdx.x;
    if (e < nEdges) {
        const int2 p = reinterpret_cast<const int2*>(eidx)[e];
        unsafeAtomicAdd(&wsum[p.y], weight[e]);
    }
}

// k2: btw[d] = sum_n wsum[n] * embed[n, d]  (dense scan over embed)
__global__ __launch_bounds__(256) void btw_kernel(
    const float* __restrict__ embed,
    const float* __restrict__ wsum,
    float* __restrict__ btw,    // [128], pre-zeroed
    int nNodes)
{
    __shared__ float sbtw[D];
    const int tid = threadIdx.x;
    for (int i = tid; i < D; i += 256) sbtw[i] = 0.f;
    __syncthreads();

    const int j = tid & 31;                       // lane within half-wave -> dims 4j..4j+3
    const int hw  = blockIdx.x * 8 + (tid >> 5);  // half-wave id
    const int nhw = gridDim.x * 8;

    float4 acc = {0.f, 0.f, 0.f, 0.f};
    for (int n = hw; n < nNodes; n += nhw) {
        const float w = wsum[n];
        const float4 v = reinterpret_cast<const float4*>(embed + (size_t)n * D)[j];
        acc.x += w * v.x;
        acc.y += w * v.y;
        acc.z += w * v.z;
        acc.w += w * v.w;
    }
    atomicAdd(&sbtw[4 * j + 0], acc.x);
    atomicAdd(&sbtw[4 * j + 1], acc.y);
    atomicAdd(&sbtw[4 * j + 2], acc.z);
    atomicAdd(&sbtw[4 * j + 3], acc.w);
    __syncthreads();
    if (tid < D) unsafeAtomicAdd(&btw[tid], sbtw[tid]);
}

// k3: snode[n] = dot(embed[n,:], btw)  (dense scan over embed)
__global__ __launch_bounds__(256) void snode_kernel(
    const float* __restrict__ embed,
    const float* __restrict__ btw,
    float* __restrict__ snode,  // [nNodes]
    int nNodes)
{
    const int tid = threadIdx.x;
    const int j = tid & 31;
    const float4 bt = reinterpret_cast<const float4*>(btw)[j];
    const int hw  = blockIdx.x * 8 + (tid >> 5);
    const int nhw = gridDim.x * 8;

    for (int n = hw; n < nNodes; n += nhw) {
        const float4 v = reinterpret_cast<const float4*>(embed + (size_t)n * D)[j];
        float s = v.x * bt.x + v.y * bt.y + v.z * bt.z + v.w * bt.w;
        #pragma unroll
        for (int m = 1; m < 32; m <<= 1)
            s += __shfl_xor(s, m, 64);
        if (j == 0) snode[n] = s;
    }
}

// k4: out[e] = sigmoid(log(snode[src_e]) + EPS)
__global__ __launch_bounds__(256) void out_kernel(
    const int* __restrict__ eidx,
    const float* __restrict__ snode,
    float* __restrict__ out,
    int nEdges)
{
    const int e = blockIdx.x * blockDim.x + threadIdx.x;
    if (e < nEdges) {
        const int2 p = reinterpret_cast<const int2*>(eidx)[e];
        const float x = logf(snode[p.x]) + EPS;
        out[e] = 1.f / (1.f + expf(-x));
    }
}

extern "C" void kernel_launch(void* const* d_in, const int* in_sizes, int n_in,
                              void* d_out, int out_size, void* d_ws, size_t ws_size,
                              hipStream_t stream) {
    const float* embed  = (const float*)d_in[0];
    const float* weight = (const float*)d_in[1];
    const int*   eidx   = (const int*)d_in[2];
    float* out = (float*)d_out;

    const int nEdges = in_sizes[1];          // weight is (E,1)
    const int nNodes = in_sizes[0] / D;      // embed is (N,128)

    float* wsum  = (float*)d_ws;             // [nNodes]
    float* btw   = wsum + nNodes;            // [128]
    float* snode = btw + D;                  // [nNodes]

    hipMemsetAsync(d_ws, 0, (size_t)(nNodes + D) * sizeof(float), stream);

    const int eBlocks = (nEdges + 255) / 256;
    wsum_kernel <<<eBlocks, 256, 0, stream>>>(weight, eidx, wsum, nEdges);
    btw_kernel  <<<512,     256, 0, stream>>>(embed, wsum, btw, nNodes);
    snode_kernel<<<1024,    256, 0, stream>>>(embed, btw, snode, nNodes);
    out_kernel  <<<eBlocks, 256, 0, stream>>>(eidx, snode, out, nEdges);
}

// Round 3
// 74.048 us; speedup vs baseline: 1.5231x; 1.0014x over previous
//
#include <hip/hip_runtime.h>

#define D 128
#define EPS 1e-5f

// k0: zero wsum[nNodes] + btw[128] (replaces pathologically slow rocclr fill)
__global__ __launch_bounds__(256) void zero_kernel(
    float4* __restrict__ p, int n4)
{
    const int i = blockIdx.x * blockDim.x + threadIdx.x;
    const int stride = gridDim.x * blockDim.x;
    const float4 z = {0.f, 0.f, 0.f, 0.f};
    for (int k = i; k < n4; k += stride) p[k] = z;
}

// k1: wsum[n] = sum of weight over edges whose dst == n
__global__ __launch_bounds__(256) void wsum_kernel(
    const float* __restrict__ weight,
    const int* __restrict__ eidx,
    float* __restrict__ wsum,   // [nNodes], pre-zeroed
    int nEdges)
{
    const int e = blockIdx.x * blockDim.x + threadIdx.x;
    if (e < nEdges) {
        const int2 p = reinterpret_cast<const int2*>(eidx)[e];
        unsafeAtomicAdd(&wsum[p.y], weight[e]);
    }
}

// k2: btw[d] = sum_n wsum[n] * embed[n, d]  (dense scan over embed)
__global__ __launch_bounds__(256) void btw_kernel(
    const float* __restrict__ embed,
    const float* __restrict__ wsum,
    float* __restrict__ btw,    // [128], pre-zeroed
    int nNodes)
{
    __shared__ float sbtw[D];
    const int tid = threadIdx.x;
    for (int i = tid; i < D; i += 256) sbtw[i] = 0.f;
    __syncthreads();

    const int j = tid & 31;                       // lane within half-wave -> dims 4j..4j+3
    const int hw  = blockIdx.x * 8 + (tid >> 5);  // half-wave id
    const int nhw = gridDim.x * 8;

    float4 acc = {0.f, 0.f, 0.f, 0.f};
    for (int n = hw; n < nNodes; n += nhw) {
        const float w = wsum[n];
        const float4 v = reinterpret_cast<const float4*>(embed + (size_t)n * D)[j];
        acc.x += w * v.x;
        acc.y += w * v.y;
        acc.z += w * v.z;
        acc.w += w * v.w;
    }
    atomicAdd(&sbtw[4 * j + 0], acc.x);
    atomicAdd(&sbtw[4 * j + 1], acc.y);
    atomicAdd(&sbtw[4 * j + 2], acc.z);
    atomicAdd(&sbtw[4 * j + 3], acc.w);
    __syncthreads();
    if (tid < D) unsafeAtomicAdd(&btw[tid], sbtw[tid]);
}

// k3: snode[n] = dot(embed[n,:], btw)  (dense scan over embed)
__global__ __launch_bounds__(256) void snode_kernel(
    const float* __restrict__ embed,
    const float* __restrict__ btw,
    float* __restrict__ snode,  // [nNodes]
    int nNodes)
{
    const int tid = threadIdx.x;
    const int j = tid & 31;
    const float4 bt = reinterpret_cast<const float4*>(btw)[j];
    const int hw  = blockIdx.x * 8 + (tid >> 5);
    const int nhw = gridDim.x * 8;

    for (int n = hw; n < nNodes; n += nhw) {
        const float4 v = reinterpret_cast<const float4*>(embed + (size_t)n * D)[j];
        float s = v.x * bt.x + v.y * bt.y + v.z * bt.z + v.w * bt.w;
        #pragma unroll
        for (int m = 1; m < 32; m <<= 1)
            s += __shfl_xor(s, m, 64);
        if (j == 0) snode[n] = s;
    }
}

// k4: out[e] = sigmoid(log(snode[src_e]) + EPS)
__global__ __launch_bounds__(256) void out_kernel(
    const int* __restrict__ eidx,
    const float* __restrict__ snode,
    float* __restrict__ out,
    int nEdges)
{
    const int e = blockIdx.x * blockDim.x + threadIdx.x;
    if (e < nEdges) {
        const int2 p = reinterpret_cast<const int2*>(eidx)[e];
        const float x = logf(snode[p.x]) + EPS;
        out[e] = 1.f / (1.f + expf(-x));
    }
}

extern "C" void kernel_launch(void* const* d_in, const int* in_sizes, int n_in,
                              void* d_out, int out_size, void* d_ws, size_t ws_size,
                              hipStream_t stream) {
    const float* embed  = (const float*)d_in[0];
    const float* weight = (const float*)d_in[1];
    const int*   eidx   = (const int*)d_in[2];
    float* out = (float*)d_out;

    const int nEdges = in_sizes[1];          // weight is (E,1)
    const int nNodes = in_sizes[0] / D;      // embed is (N,128)

    float* wsum  = (float*)d_ws;             // [nNodes]
    float* btw   = wsum + nNodes;            // [128]
    float* snode = btw + D;                  // [nNodes]

    const int nZero4 = (nNodes + D + 3) / 4; // float4 count (wsum+btw contiguous)
    const int eBlocks = (nEdges + 255) / 256;

    zero_kernel <<<(nZero4 + 255) / 256, 256, 0, stream>>>((float4*)d_ws, nZero4);
    wsum_kernel <<<eBlocks, 256, 0, stream>>>(weight, eidx, wsum, nEdges);
    btw_kernel  <<<512,     256, 0, stream>>>(embed, wsum, btw, nNodes);
    snode_kernel<<<1024,    256, 0, stream>>>(embed, btw, snode, nNodes);
    out_kernel  <<<eBlocks, 256, 0, stream>>>(eidx, snode, out, nEdges);
}